// Round 6
// baseline (144.754 us; speedup 1.0000x reference)
//
#include <hip/hip_runtime.h>

#define NPTS 65536

__device__ __forceinline__ float bf_lo(unsigned u) { return __uint_as_float(u << 16); }
__device__ __forceinline__ float bf_hi(unsigned u) { return __uint_as_float(u & 0xFFFF0000u); }
__device__ __forceinline__ unsigned short f2bf(float f) {      // RNE round
    unsigned u = __float_as_uint(f);
    return (unsigned short)((u + 0x7FFFu + ((u >> 16) & 1u)) >> 16);
}
__device__ __forceinline__ void unpack8(uint4 v, float* o) {
    o[0] = bf_lo(v.x); o[1] = bf_hi(v.x); o[2] = bf_lo(v.y); o[3] = bf_hi(v.y);
    o[4] = bf_lo(v.z); o[5] = bf_hi(v.z); o[6] = bf_lo(v.w); o[7] = bf_hi(v.w);
}
__device__ __forceinline__ float dot8q(uint4 q, const float* x) {
    float s;
    s  = bf_lo(q.x) * x[0] + bf_hi(q.x) * x[1];
    s += bf_lo(q.y) * x[2] + bf_hi(q.y) * x[3];
    s += bf_lo(q.z) * x[4] + bf_hi(q.z) * x[5];
    s += bf_lo(q.w) * x[6] + bf_hi(q.w) * x[7];
    return s;
}

// ---------------- Kernel 1: M = WQ^T * WK for both attentions ----------------
__global__ __launch_bounds__(256) void k_matM(const float* __restrict__ WQa,
                                              const float* __restrict__ WKa,
                                              const float* __restrict__ WQe,
                                              const float* __restrict__ WKe,
                                              float* __restrict__ M) {
    __shared__ float WKs[4096];       // full WK, row-major [d][e], stride 64
    __shared__ float WQs[64][16];     // WQ columns c0..c0+15
    const int which = blockIdx.x >> 2;
    const int c0 = (blockIdx.x & 3) * 16;
    const float* WQ = which ? WQe : WQa;
    const float* WK = which ? WKe : WKa;
    const int t = threadIdx.x;
    #pragma unroll
    for (int i = 0; i < 16; ++i) WKs[t + i * 256] = WK[t + i * 256];
    #pragma unroll
    for (int i = 0; i < 4; ++i) {
        const int id = t + i * 256;
        WQs[id >> 4][id & 15] = WQ[(id >> 4) * 64 + c0 + (id & 15)];
    }
    __syncthreads();
    const int cc = t >> 4;
    const int eg = t & 15;
    float4 acc = make_float4(0.f, 0.f, 0.f, 0.f);
    #pragma unroll
    for (int d = 0; d < 64; ++d) {
        const float wq = WQs[d][cc];
        const float4 wk = *reinterpret_cast<const float4*>(&WKs[d * 64 + eg * 4]);
        acc.x += wq * wk.x; acc.y += wq * wk.y;
        acc.z += wq * wk.z; acc.w += wq * wk.w;
    }
    *reinterpret_cast<float4*>(&M[which * 4096 + (c0 + cc) * 64 + eg * 4]) = acc;
}

// ------- Kernel 2: fused pack (featT bf16) + qeff (bf16) ---------------------
__global__ __launch_bounds__(256) void k_prep(const float* __restrict__ spa,
                                              const float* __restrict__ spe,
                                              const float* __restrict__ M,
                                              unsigned short* __restrict__ featT,
                                              unsigned short* __restrict__ qeff) {
    __shared__ float tile[64][132];   // f32 staging, float4-aligned rows
    const int n0 = blockIdx.x * 64;
    const int t = threadIdx.x;
    {
        const int p = t & 63;
        const int c0 = t >> 6;
        #pragma unroll
        for (int i = 0; i < 32; ++i) {
            const int c = c0 + (i << 2);
            tile[p][c] = (c < 64) ? spa[c * NPTS + n0 + p]
                                  : spe[(c - 64) * NPTS + n0 + p];
        }
    }
    __syncthreads();
    const int c = t & 127;
    const int p0 = t >> 7;
    #pragma unroll
    for (int i = 0; i < 32; ++i) {    // bf16 pack-write (coalesced)
        const int p = p0 + (i << 1);
        featT[(size_t)(n0 + p) * 128 + c] = f2bf(tile[p][c]);
    }
    const int which = c >> 6;
    const int e = c & 63;
    float mcol[64];
    #pragma unroll
    for (int cc = 0; cc < 64; ++cc) mcol[cc] = M[which * 4096 + cc * 64 + e];
    for (int i = 0; i < 32; ++i) {
        const int p = p0 + (i << 1);
        const float4* fr = reinterpret_cast<const float4*>(&tile[p][which << 6]);
        float a0 = 0.f, a1 = 0.f, a2 = 0.f, a3 = 0.f;   // ILP-4
        #pragma unroll
        for (int c4 = 0; c4 < 16; c4 += 4) {
            const float4 v0 = fr[c4],     v1 = fr[c4 + 1];
            const float4 v2 = fr[c4 + 2], v3 = fr[c4 + 3];
            a0 += v0.x*mcol[4*c4]    + v0.y*mcol[4*c4+1]  + v0.z*mcol[4*c4+2]  + v0.w*mcol[4*c4+3];
            a1 += v1.x*mcol[4*c4+4]  + v1.y*mcol[4*c4+5]  + v1.z*mcol[4*c4+6]  + v1.w*mcol[4*c4+7];
            a2 += v2.x*mcol[4*c4+8]  + v2.y*mcol[4*c4+9]  + v2.z*mcol[4*c4+10] + v2.w*mcol[4*c4+11];
            a3 += v3.x*mcol[4*c4+12] + v3.y*mcol[4*c4+13] + v3.z*mcol[4*c4+14] + v3.w*mcol[4*c4+15];
        }
        qeff[(size_t)(n0 + p) * 128 + c] = f2bf((a0 + a1) + (a2 + a3));
    }
}

// ------ Kernel 3: FUSED attention + WV-projection + residual + write ---------
// Block = 4 waves x 16 sequential points = 64 consecutive points.
// LDS: red [4][16][76] f32 (19456 B) | sctx [64][128] f32 (32768 B),
//      ctxT [128][67] f32 (34304 B) overlays sctx after a barrier.
__global__ __launch_bounds__(256, 3) void k_fused(const unsigned short* __restrict__ featT,
                                                  const unsigned short* __restrict__ qeff,
                                                  const int* __restrict__ idx,
                                                  const float* __restrict__ spa,
                                                  const float* __restrict__ spe,
                                                  const float* __restrict__ WVa,
                                                  const float* __restrict__ bVa,
                                                  const float* __restrict__ WVe,
                                                  const float* __restrict__ bVe,
                                                  float* __restrict__ out) {
    __shared__ float smem[13440];          // 53760 B total
    float* red  = smem;                    // [4][16][76]
    float* sctx = smem + 4864;             // [64][128]
    float* ctxT = smem + 4864;             // [128][67] (overlay, after barrier)
    const int t = threadIdx.x;
    const int wave = t >> 6;
    const int lane = t & 63;
    const int n0 = blockIdx.x * 64;
    const int k = lane >> 2;               // neighbor owned by this lane
    const int c4 = lane & 3;               // channel quarter (16 channels)
    float* myred = red + wave * 1216;      // [16][76]

    // ---------------- attention phase: 16 points per wave ----------------
    for (int it = 0; it < 16; ++it) {
        const int pt = wave * 16 + it;     // block-local point
        const int n = n0 + pt;
        const int j = idx[n * 16 + k];     // 4 lanes same addr -> broadcast
        const uint4* fx = reinterpret_cast<const uint4*>(featT + (size_t)j * 128);
        const uint4 A0 = fx[2*c4],     A1 = fx[2*c4 + 1];      // spa 16 ch
        const uint4 E0 = fx[8 + 2*c4], E1 = fx[8 + 2*c4 + 1];  // spe 16 ch
        const uint4* qx = reinterpret_cast<const uint4*>(qeff + (size_t)n * 128);
        const uint4 QA0 = qx[2*c4],     QA1 = qx[2*c4 + 1];
        const uint4 QE0 = qx[8 + 2*c4], QE1 = qx[8 + 2*c4 + 1];

        float xa[16], xe[16];
        unpack8(A0, xa); unpack8(A1, xa + 8);
        unpack8(E0, xe); unpack8(E1, xe + 8);

        // scores: spa att = q_spa . x_spe ; spe att = q_spe . x_spa
        float pa = dot8q(QA0, xe) + dot8q(QA1, xe + 8);
        float pe = dot8q(QE0, xa) + dot8q(QE1, xa + 8);
        pa += __shfl_xor(pa, 1); pa += __shfl_xor(pa, 2);   // reduce over c4
        pe += __shfl_xor(pe, 1); pe += __shfl_xor(pe, 2);
        // |score| <= ~0.2 by construction (0.02-scale weights) -> exp without
        // max subtraction is numerically safe.
        const float ea = __expf(pa * 0.125f);
        const float ee = __expf(pe * 0.125f);
        float da = ea, de = ee;
        #pragma unroll
        for (int m = 4; m < 64; m <<= 1) {  // sum over the 16 k, each once
            da += __shfl_xor(da, m);
            de += __shfl_xor(de, m);
        }
        const float wA = ea / da;
        const float wB = ee / de;

        float4* row4 = reinterpret_cast<float4*>(myred + k * 76 + c4 * 16);
        // ---- pass 1: ctx_spa from spe half ----
        row4[0] = make_float4(wA*xe[0],  wA*xe[1],  wA*xe[2],  wA*xe[3]);
        row4[1] = make_float4(wA*xe[4],  wA*xe[5],  wA*xe[6],  wA*xe[7]);
        row4[2] = make_float4(wA*xe[8],  wA*xe[9],  wA*xe[10], wA*xe[11]);
        row4[3] = make_float4(wA*xe[12], wA*xe[13], wA*xe[14], wA*xe[15]);
        asm volatile("s_waitcnt lgkmcnt(0)" ::: "memory");  // wave-internal fence
        float sumA = 0.f;
        #pragma unroll
        for (int kk = 0; kk < 16; ++kk) sumA += myred[kk * 76 + lane];
        sctx[pt * 128 + lane] = sumA;
        asm volatile("s_waitcnt lgkmcnt(0)" ::: "memory");  // reads before overwrite
        // ---- pass 2: ctx_spe from spa half ----
        row4[0] = make_float4(wB*xa[0],  wB*xa[1],  wB*xa[2],  wB*xa[3]);
        row4[1] = make_float4(wB*xa[4],  wB*xa[5],  wB*xa[6],  wB*xa[7]);
        row4[2] = make_float4(wB*xa[8],  wB*xa[9],  wB*xa[10], wB*xa[11]);
        row4[3] = make_float4(wB*xa[12], wB*xa[13], wB*xa[14], wB*xa[15]);
        asm volatile("s_waitcnt lgkmcnt(0)" ::: "memory");
        float sumE = 0.f;
        #pragma unroll
        for (int kk = 0; kk < 16; ++kk) sumE += myred[kk * 76 + lane];
        sctx[pt * 128 + 64 + lane] = sumE;
        asm volatile("s_waitcnt lgkmcnt(0)" ::: "memory");  // reads before next-iter overwrite
    }

    // ---------------- epilogue: ctx = WV*s + b, residual, write ----------
    const int d = t & 127;                 // output channel
    const int which = d >> 6;
    const int dd = d & 63;
    const int p0 = t >> 7;
    const float* WV = which ? WVe : WVa;
    float wrow[64];
    #pragma unroll
    for (int e4 = 0; e4 < 16; ++e4) {      // global loads, L1-hot after 1st block
        const float4 w4 = *reinterpret_cast<const float4*>(WV + dd * 64 + e4 * 4);
        wrow[4*e4] = w4.x; wrow[4*e4+1] = w4.y; wrow[4*e4+2] = w4.z; wrow[4*e4+3] = w4.w;
    }
    const float bias = which ? bVe[dd] : bVa[dd];
    __syncthreads();                       // all sctx rows written
    float acc[32];
    #pragma unroll
    for (int i = 0; i < 32; ++i) {
        const int p = p0 + (i << 1);
        const float4* sr = reinterpret_cast<const float4*>(sctx + p * 128 + (which << 6));
        float a = bias;
        #pragma unroll
        for (int e4 = 0; e4 < 16; ++e4) {  // broadcast reads
            const float4 v = sr[e4];
            a += v.x * wrow[4*e4] + v.y * wrow[4*e4+1] + v.z * wrow[4*e4+2] + v.w * wrow[4*e4+3];
        }
        acc[i] = a;
    }
    __syncthreads();                       // sctx reads done -> ctxT may overlay
    #pragma unroll
    for (int i = 0; i < 32; ++i) {
        ctxT[d * 67 + p0 + (i << 1)] = acc[i];   // stride 67: 2-way free
    }
    __syncthreads();
    {
        const int p = t & 63;
        const int d0 = t >> 6;
        #pragma unroll
        for (int i = 0; i < 32; ++i) {
            const int ch = d0 + (i << 2);
            const float f = (ch < 64) ? spa[ch * NPTS + n0 + p]
                                      : spe[(ch - 64) * NPTS + n0 + p];
            out[(size_t)ch * NPTS + n0 + p] = f + ctxT[ch * 67 + p];
        }
    }
}

extern "C" void kernel_launch(void* const* d_in, const int* in_sizes, int n_in,
                              void* d_out, int out_size, void* d_ws, size_t ws_size,
                              hipStream_t stream) {
    const float* spa = (const float*)d_in[0];
    const float* spe = (const float*)d_in[1];
    const int* idx   = (const int*)d_in[2];
    const float* WQa = (const float*)d_in[3];
    const float* WKa = (const float*)d_in[4];
    const float* WVa = (const float*)d_in[5];
    const float* bVa = (const float*)d_in[6];
    const float* WQe = (const float*)d_in[7];
    const float* WKe = (const float*)d_in[8];
    const float* WVe = (const float*)d_in[9];
    const float* bVe = (const float*)d_in[10];
    float* out = (float*)d_out;

    char* ws = (char*)d_ws;
    unsigned short* featT = (unsigned short*)(ws);              // 16.78 MB bf16 [N][128]
    unsigned short* qeff  = (unsigned short*)(ws + 16777216);   // 16.78 MB bf16 [N][128]
    float* Mmat = (float*)(ws + 33554432);                      // 32 KB f32 [2][64][64]

    k_matM<<<8, 256, 0, stream>>>(WQa, WKa, WQe, WKe, Mmat);
    k_prep<<<1024, 256, 0, stream>>>(spa, spe, Mmat, featT, qeff);
    k_fused<<<1024, 256, 0, stream>>>(featT, qeff, idx, spa, spe,
                                      WVa, bVa, WVe, bVe, out);
}

// Round 7
// 109.864 us; speedup vs baseline: 1.3176x; 1.3176x over previous
//
#include <hip/hip_runtime.h>

#define NPTS 65536

__device__ __forceinline__ float bf_lo(unsigned u) { return __uint_as_float(u << 16); }
__device__ __forceinline__ float bf_hi(unsigned u) { return __uint_as_float(u & 0xFFFF0000u); }
__device__ __forceinline__ unsigned short f2bf(float f) {      // RNE round
    unsigned u = __float_as_uint(f);
    return (unsigned short)((u + 0x7FFFu + ((u >> 16) & 1u)) >> 16);
}
__device__ __forceinline__ void unpack8(uint4 v, float* o) {
    o[0] = bf_lo(v.x); o[1] = bf_hi(v.x); o[2] = bf_lo(v.y); o[3] = bf_hi(v.y);
    o[4] = bf_lo(v.z); o[5] = bf_hi(v.z); o[6] = bf_lo(v.w); o[7] = bf_hi(v.w);
}
__device__ __forceinline__ float dot8q(uint4 q, const float* x) {
    float s;
    s  = bf_lo(q.x) * x[0] + bf_hi(q.x) * x[1];
    s += bf_lo(q.y) * x[2] + bf_hi(q.y) * x[3];
    s += bf_lo(q.z) * x[4] + bf_hi(q.z) * x[5];
    s += bf_lo(q.w) * x[6] + bf_hi(q.w) * x[7];
    return s;
}

// ---------------- Kernel 1: M = WQ^T * WK for both attentions ----------------
__global__ __launch_bounds__(256) void k_matM(const float* __restrict__ WQa,
                                              const float* __restrict__ WKa,
                                              const float* __restrict__ WQe,
                                              const float* __restrict__ WKe,
                                              float* __restrict__ M) {
    __shared__ float WKs[4096];       // full WK, row-major [d][e], stride 64
    __shared__ float WQs[64][16];     // WQ columns c0..c0+15
    const int which = blockIdx.x >> 2;
    const int c0 = (blockIdx.x & 3) * 16;
    const float* WQ = which ? WQe : WQa;
    const float* WK = which ? WKe : WKa;
    const int t = threadIdx.x;
    #pragma unroll
    for (int i = 0; i < 16; ++i) WKs[t + i * 256] = WK[t + i * 256];
    #pragma unroll
    for (int i = 0; i < 4; ++i) {
        const int id = t + i * 256;
        WQs[id >> 4][id & 15] = WQ[(id >> 4) * 64 + c0 + (id & 15)];
    }
    __syncthreads();
    const int cc = t >> 4;
    const int eg = t & 15;
    float4 acc = make_float4(0.f, 0.f, 0.f, 0.f);
    #pragma unroll
    for (int d = 0; d < 64; ++d) {
        const float wq = WQs[d][cc];
        const float4 wk = *reinterpret_cast<const float4*>(&WKs[d * 64 + eg * 4]);
        acc.x += wq * wk.x; acc.y += wq * wk.y;
        acc.z += wq * wk.z; acc.w += wq * wk.w;
    }
    *reinterpret_cast<float4*>(&M[which * 4096 + (c0 + cc) * 64 + eg * 4]) = acc;
}

// ------- Kernel 2: fused pack (featT bf16) + qeff (bf16) ---------------------
__global__ __launch_bounds__(256) void k_prep(const float* __restrict__ spa,
                                              const float* __restrict__ spe,
                                              const float* __restrict__ M,
                                              unsigned short* __restrict__ featT,
                                              unsigned short* __restrict__ qeff) {
    __shared__ float tile[64][132];   // f32 staging, float4-aligned rows
    const int n0 = blockIdx.x * 64;
    const int t = threadIdx.x;
    {
        const int p = t & 63;
        const int c0 = t >> 6;
        #pragma unroll
        for (int i = 0; i < 32; ++i) {
            const int c = c0 + (i << 2);
            tile[p][c] = (c < 64) ? spa[c * NPTS + n0 + p]
                                  : spe[(c - 64) * NPTS + n0 + p];
        }
    }
    __syncthreads();
    const int c = t & 127;
    const int p0 = t >> 7;
    #pragma unroll
    for (int i = 0; i < 32; ++i) {    // bf16 pack-write (coalesced)
        const int p = p0 + (i << 1);
        featT[(size_t)(n0 + p) * 128 + c] = f2bf(tile[p][c]);
    }
    const int which = c >> 6;
    const int e = c & 63;
    float mcol[64];
    #pragma unroll
    for (int cc = 0; cc < 64; ++cc) mcol[cc] = M[which * 4096 + cc * 64 + e];
    for (int i = 0; i < 32; ++i) {
        const int p = p0 + (i << 1);
        const float4* fr = reinterpret_cast<const float4*>(&tile[p][which << 6]);
        float a0 = 0.f, a1 = 0.f, a2 = 0.f, a3 = 0.f;   // ILP-4
        #pragma unroll
        for (int c4 = 0; c4 < 16; c4 += 4) {
            const float4 v0 = fr[c4],     v1 = fr[c4 + 1];
            const float4 v2 = fr[c4 + 2], v3 = fr[c4 + 3];
            a0 += v0.x*mcol[4*c4]    + v0.y*mcol[4*c4+1]  + v0.z*mcol[4*c4+2]  + v0.w*mcol[4*c4+3];
            a1 += v1.x*mcol[4*c4+4]  + v1.y*mcol[4*c4+5]  + v1.z*mcol[4*c4+6]  + v1.w*mcol[4*c4+7];
            a2 += v2.x*mcol[4*c4+8]  + v2.y*mcol[4*c4+9]  + v2.z*mcol[4*c4+10] + v2.w*mcol[4*c4+11];
            a3 += v3.x*mcol[4*c4+12] + v3.y*mcol[4*c4+13] + v3.z*mcol[4*c4+14] + v3.w*mcol[4*c4+15];
        }
        qeff[(size_t)(n0 + p) * 128 + c] = f2bf((a0 + a1) + (a2 + a3));
    }
}

// ------ Kernel 3: FUSED attention + WV-projection + residual + write ---------
// Block = 4 waves x 16 sequential points = 64 consecutive points.
// LDS: sctx [64][128] f32 (32768 B), overlaid after a barrier by
//      ctxT [128][67] f32 (34304 B). Static total = 34304 B -> 4 blocks/CU.
// Attention phase is LDS-free (shfl reduce-scatter), no fences in the loop.
__global__ __launch_bounds__(256, 4) void k_fused(const unsigned short* __restrict__ featT,
                                                  const unsigned short* __restrict__ qeff,
                                                  const int* __restrict__ idx,
                                                  const float* __restrict__ spa,
                                                  const float* __restrict__ spe,
                                                  const float* __restrict__ WVa,
                                                  const float* __restrict__ bVa,
                                                  const float* __restrict__ WVe,
                                                  const float* __restrict__ bVe,
                                                  float* __restrict__ out) {
    __shared__ float smem[8576];           // 34304 B
    float* sctx = smem;                    // [64][128] (phase A/B)
    float* ctxT = smem;                    // [128][67] (overlay, phase C/D)
    const int t = threadIdx.x;
    const int wave = t >> 6;
    const int lane = t & 63;
    const int n0 = blockIdx.x * 64;
    const int k = lane >> 2;               // neighbor owned by this lane
    const int c4 = lane & 3;               // channel quarter (16 channels)
    // final channel owned after reduce-scatter (bijection over 64 lanes)
    const int cfin = c4 * 16 + ((lane >> 2) & 1) * 8 + ((lane >> 3) & 1) * 4
                   + ((lane >> 4) & 1) * 2 + ((lane >> 5) & 1) * 1;

    // ---------------- attention phase: 16 points per wave ----------------
    for (int it = 0; it < 16; ++it) {
        const int pt = wave * 16 + it;     // block-local point
        const int n = n0 + pt;
        const int j = idx[n * 16 + k];     // 4 lanes same addr -> broadcast
        const uint4* fx = reinterpret_cast<const uint4*>(featT + (size_t)j * 128);
        const uint4 A0 = fx[2*c4],     A1 = fx[2*c4 + 1];      // spa 16 ch
        const uint4 E0 = fx[8 + 2*c4], E1 = fx[8 + 2*c4 + 1];  // spe 16 ch
        const uint4* qx = reinterpret_cast<const uint4*>(qeff + (size_t)n * 128);
        const uint4 QA0 = qx[2*c4],     QA1 = qx[2*c4 + 1];
        const uint4 QE0 = qx[8 + 2*c4], QE1 = qx[8 + 2*c4 + 1];

        float xa[16], xe[16];
        unpack8(A0, xa); unpack8(A1, xa + 8);
        unpack8(E0, xe); unpack8(E1, xe + 8);

        // scores: spa att = q_spa . x_spe ; spe att = q_spe . x_spa
        float pa = dot8q(QA0, xe) + dot8q(QA1, xe + 8);
        float pe = dot8q(QE0, xa) + dot8q(QE1, xa + 8);
        pa += __shfl_xor(pa, 1); pa += __shfl_xor(pa, 2);   // reduce over c4
        pe += __shfl_xor(pe, 1); pe += __shfl_xor(pe, 2);
        // |score| small by construction (0.02-scale weights) -> exp safe
        const float ea = __expf(pa * 0.125f);
        const float ee = __expf(pe * 0.125f);
        float da = ea, de = ee;
        #pragma unroll
        for (int m = 4; m < 64; m <<= 1) {  // sum over the 16 k, each once
            da += __shfl_xor(da, m);
            de += __shfl_xor(de, m);
        }
        const float wA = ea / da;
        const float wB = ee / de;

        // weighted vectors: yA (ctx_spa from spe half), yB (ctx_spe from spa)
        float yA[16], yB[16];
        #pragma unroll
        for (int i = 0; i < 16; ++i) { yA[i] = wA * xe[i]; yB[i] = wB * xa[i]; }

        // in-register reduce-scatter over k bits (masks 4,8,16,32):
        // halve channel set 16->8->4->2->1, summing with partner.
        #pragma unroll
        for (int i = 0; i < 8; ++i) {
            const bool up = (lane & 4) != 0;
            float sA = up ? yA[i] : yA[i + 8];
            float sB = up ? yB[i] : yB[i + 8];
            float gA = __shfl_xor(sA, 4);
            float gB = __shfl_xor(sB, 4);
            yA[i] = (up ? yA[i + 8] : yA[i]) + gA;
            yB[i] = (up ? yB[i + 8] : yB[i]) + gB;
        }
        #pragma unroll
        for (int i = 0; i < 4; ++i) {
            const bool up = (lane & 8) != 0;
            float sA = up ? yA[i] : yA[i + 4];
            float sB = up ? yB[i] : yB[i + 4];
            float gA = __shfl_xor(sA, 8);
            float gB = __shfl_xor(sB, 8);
            yA[i] = (up ? yA[i + 4] : yA[i]) + gA;
            yB[i] = (up ? yB[i + 4] : yB[i]) + gB;
        }
        #pragma unroll
        for (int i = 0; i < 2; ++i) {
            const bool up = (lane & 16) != 0;
            float sA = up ? yA[i] : yA[i + 2];
            float sB = up ? yB[i] : yB[i + 2];
            float gA = __shfl_xor(sA, 16);
            float gB = __shfl_xor(sB, 16);
            yA[i] = (up ? yA[i + 2] : yA[i]) + gA;
            yB[i] = (up ? yB[i + 2] : yB[i]) + gB;
        }
        {
            const bool up = (lane & 32) != 0;
            float sA = up ? yA[0] : yA[1];
            float sB = up ? yB[0] : yB[1];
            float gA = __shfl_xor(sA, 32);
            float gB = __shfl_xor(sB, 32);
            yA[0] = (up ? yA[1] : yA[0]) + gA;
            yB[0] = (up ? yB[1] : yB[0]) + gB;
        }
        // lane owns channel cfin: 2 f32 stores, 2-way banked, no fence needed
        sctx[pt * 128 + cfin]      = yA[0];
        sctx[pt * 128 + 64 + cfin] = yB[0];
    }

    // ---------------- epilogue: ctx = WV*s + b, residual, write ----------
    const int d = t & 127;                 // output channel
    const int which = d >> 6;
    const int dd = d & 63;
    const int p0 = t >> 7;
    const float* WV = which ? WVe : WVa;
    float wrow[64];
    #pragma unroll
    for (int e4 = 0; e4 < 16; ++e4) {      // global loads, L2-hot
        const float4 w4 = *reinterpret_cast<const float4*>(WV + dd * 64 + e4 * 4);
        wrow[4*e4] = w4.x; wrow[4*e4+1] = w4.y; wrow[4*e4+2] = w4.z; wrow[4*e4+3] = w4.w;
    }
    const float bias = which ? bVe[dd] : bVa[dd];
    __syncthreads();                       // all sctx rows written
    float acc[32];
    #pragma unroll
    for (int i = 0; i < 32; ++i) {
        const int p = p0 + (i << 1);
        const float4* sr = reinterpret_cast<const float4*>(sctx + p * 128 + (which << 6));
        float a = bias;
        #pragma unroll
        for (int e4 = 0; e4 < 16; ++e4) {  // broadcast reads
            const float4 v = sr[e4];
            a += v.x * wrow[4*e4] + v.y * wrow[4*e4+1] + v.z * wrow[4*e4+2] + v.w * wrow[4*e4+3];
        }
        acc[i] = a;
    }
    __syncthreads();                       // sctx reads done -> ctxT may overlay
    #pragma unroll
    for (int i = 0; i < 32; ++i) {
        ctxT[d * 67 + p0 + (i << 1)] = acc[i];   // stride 67: 2-way free
    }
    __syncthreads();
    {
        const int p = t & 63;
        const int d0 = t >> 6;
        #pragma unroll
        for (int i = 0; i < 32; ++i) {
            const int ch = d0 + (i << 2);
            const float f = (ch < 64) ? spa[ch * NPTS + n0 + p]
                                      : spe[(ch - 64) * NPTS + n0 + p];
            out[(size_t)ch * NPTS + n0 + p] = f + ctxT[ch * 67 + p];
        }
    }
}

extern "C" void kernel_launch(void* const* d_in, const int* in_sizes, int n_in,
                              void* d_out, int out_size, void* d_ws, size_t ws_size,
                              hipStream_t stream) {
    const float* spa = (const float*)d_in[0];
    const float* spe = (const float*)d_in[1];
    const int* idx   = (const int*)d_in[2];
    const float* WQa = (const float*)d_in[3];
    const float* WKa = (const float*)d_in[4];
    const float* WVa = (const float*)d_in[5];
    const float* bVa = (const float*)d_in[6];
    const float* WQe = (const float*)d_in[7];
    const float* WKe = (const float*)d_in[8];
    const float* WVe = (const float*)d_in[9];
    const float* bVe = (const float*)d_in[10];
    float* out = (float*)d_out;

    char* ws = (char*)d_ws;
    unsigned short* featT = (unsigned short*)(ws);              // 16.78 MB bf16 [N][128]
    unsigned short* qeff  = (unsigned short*)(ws + 16777216);   // 16.78 MB bf16 [N][128]
    float* Mmat = (float*)(ws + 33554432);                      // 32 KB f32 [2][64][64]

    k_matM<<<8, 256, 0, stream>>>(WQa, WKa, WQe, WKe, Mmat);
    k_prep<<<1024, 256, 0, stream>>>(spa, spe, Mmat, featT, qeff);
    k_fused<<<1024, 256, 0, stream>>>(featT, qeff, idx, spa, spe,
                                      WVa, bVa, WVe, bVe, out);
}